// Round 4
// baseline (412.961 us; speedup 1.0000x reference)
//
#include <hip/hip_runtime.h>
#include <stdint.h>

#define B_ 4
#define S_ 1024
#define HID_ 1024
#define H_ 16
#define DH_ 64
#define NDIST 33
// SCALE * log2(e) folded into Q at proj epilogue; softmax = exp2(s + rq)
#define EFACT 0.18033688f

typedef unsigned short u16;
typedef __attribute__((ext_vector_type(8))) short short8;
typedef __attribute__((ext_vector_type(4))) float floatx4;

static __device__ __forceinline__ float bf2f(u16 u) {
  union { unsigned int i; float f; } v; v.i = ((unsigned int)u) << 16; return v.f;
}
static __device__ __forceinline__ u16 f2bf(float x) {
  union { float f; unsigned int i; } v; v.f = x;
  return (u16)((v.i + 0x7FFFu + ((v.i >> 16) & 1u)) >> 16);
}
static __device__ __forceinline__ floatx4 mfma_bf16(short8 a, short8 b, floatx4 c) {
  return __builtin_amdgcn_mfma_f32_16x16x32_bf16(a, b, c, 0, 0, 0);
}
static __device__ __forceinline__ float exp2_fast(float x) {
#if __has_builtin(__builtin_amdgcn_exp2f)
  return __builtin_amdgcn_exp2f(x);
#else
  return __expf(x * 0.6931471805599453f);
#endif
}

// conv region element offsets (u16 units)
#define OFF_QB   0
#define OFF_KB   4194304
#define OFF_VB   8388608
#define OFF_BQ   12582912
#define OFF_BK   12583936
#define OFF_BV   12584960
#define OFF_RELK 12585984
#define OFF_RELV 12588096
#define OFF_FCW  12590208
#define OFF_FCB  13638784
#define CONV_TOT 13639808

struct SrcPtrs { const void* p[10]; };

// ---------------------------------------------------------------------------
// Dtype detector: fp32 read as u16 pairs -> even halves are mantissa bits ->
// huge as bf16. flag=1 means fp32 inputs.
// ---------------------------------------------------------------------------
__global__ __launch_bounds__(256) void detect_kernel(const u16* __restrict__ q,
                                                     int* __restrict__ flag) {
  __shared__ float red[256];
  float m = 0.f;
  for (int i = threadIdx.x; i < 8192; i += 256) {
    float v = fabsf(bf2f(q[2 * i]));
    m = fmaxf(m, (v < 1e30f) ? v : 1e20f);
  }
  red[threadIdx.x] = m;
  __syncthreads();
  for (int s = 128; s > 0; s >>= 1) {
    if (threadIdx.x < (unsigned)s) red[threadIdx.x] = fmaxf(red[threadIdx.x], red[threadIdx.x + s]);
    __syncthreads();
  }
  if (threadIdx.x == 0) *flag = (red[0] > 1e4f) ? 1 : 0;
}

// ---------------------------------------------------------------------------
// Convert q/k/v inputs + biases / rel tables / fcW to bf16 (copy if bf16).
// ---------------------------------------------------------------------------
__global__ __launch_bounds__(256) void convert_kernel(SrcPtrs srcs,
                                                      const int* __restrict__ flag,
                                                      u16* __restrict__ dst) {
  constexpr int segsz[10] = {4194304,4194304,4194304,1024,1024,1024,2112,2112,1048576,1024};
  constexpr int cumE[10]  = {OFF_QB,OFF_KB,OFF_VB,OFF_BQ,OFF_BK,OFF_BV,OFF_RELK,OFF_RELV,OFF_FCW,OFF_FCB};
  constexpr int cumB[10]  = {0,4096,8192,12288,12289,12290,12291,12294,12297,13321};
  const int bid = blockIdx.x;
  int t = 0;
  #pragma unroll
  for (int i = 1; i < 10; ++i) if (bid >= cumB[i]) t = i;
  const int chunk = (bid - cumB[t]) * 1024 + threadIdx.x * 4;
  if (chunk >= segsz[t]) return;
  __align__(8) u16 o[4];
  if (*flag) {
    const float* s = (const float*)srcs.p[t];
    float4 v = *(const float4*)(s + chunk);
    o[0] = f2bf(v.x); o[1] = f2bf(v.y); o[2] = f2bf(v.z); o[3] = f2bf(v.w);
  } else {
    const u16* s = (const u16*)srcs.p[t];
    *(uint2*)o = *(const uint2*)(s + chunk);
  }
  *(uint2*)(dst + cumE[t] + chunk) = *(const uint2*)o;
}

// ---------------------------------------------------------------------------
// W transpose: raw W [h][d][e] (fp32 or bf16) -> wt[z][h*64+e][d] bf16.
// ---------------------------------------------------------------------------
__global__ __launch_bounds__(256) void wtrans_kernel(
    const void* __restrict__ Wq, const void* __restrict__ Wk, const void* __restrict__ Wv,
    const int* __restrict__ flag, u16* __restrict__ wt)
{
  const int dt = blockIdx.x, h = blockIdx.y, z = blockIdx.z;
  const void* W = (z == 0) ? Wq : (z == 1) ? Wk : Wv;
  const int tid = threadIdx.x;
  const int isf = *flag;
  __shared__ __align__(16) u16 t_l[64 * 72];

  #pragma unroll
  for (int i = 0; i < 2; ++i) {
    int g = tid + 256 * i;
    int d = g & 63, e8 = (g >> 6) * 8;
    size_t off = ((size_t)h * HID_ + dt * 64 + d) * DH_ + e8;
    __align__(16) u16 tmp[8];
    if (isf) {
      const float* Wf = (const float*)W + off;
      float4 v0 = *(const float4*)Wf;
      float4 v1 = *(const float4*)(Wf + 4);
      tmp[0]=f2bf(v0.x); tmp[1]=f2bf(v0.y); tmp[2]=f2bf(v0.z); tmp[3]=f2bf(v0.w);
      tmp[4]=f2bf(v1.x); tmp[5]=f2bf(v1.y); tmp[6]=f2bf(v1.z); tmp[7]=f2bf(v1.w);
    } else {
      *(uint4*)tmp = *(const uint4*)((const u16*)W + off);
    }
    #pragma unroll
    for (int j = 0; j < 8; ++j) {
      int e = e8 + j;
      t_l[e * 72 + (((d >> 3) ^ (e & 7)) << 3) + (d & 7)] = tmp[j];
    }
  }
  __syncthreads();
  {
    int e = tid >> 2, c0 = (tid & 3) * 2;
    u16* dst = wt + ((size_t)(z * H_ + h) * DH_ + e) * HID_ + dt * 64;
    uint4 x0 = *(const uint4*)(t_l + e * 72 + (((c0    ) ^ (e & 7)) << 3));
    uint4 x1 = *(const uint4*)(t_l + e * 72 + (((c0 + 1) ^ (e & 7)) << 3));
    *(uint4*)(dst + c0 * 8)     = x0;
    *(uint4*)(dst + c0 * 8 + 8) = x1;
  }
}

// ---------------------------------------------------------------------------
// V transpose: vw [b][h][s][e] bf16 -> vt [b][h][e][s] bf16.
// grid (16 s-tiles, 16 h, 4 b), block 256.
// ---------------------------------------------------------------------------
__global__ __launch_bounds__(256) void vtrans_kernel(
    const u16* __restrict__ vw, u16* __restrict__ vt)
{
  const int st = blockIdx.x, h = blockIdx.y, b = blockIdx.z;
  const int tid = threadIdx.x;
  const u16* src = vw + (((size_t)(b * H_ + h)) * S_ + st * 64) * DH_;
  __shared__ __align__(16) u16 t_l[64 * 72];

  #pragma unroll
  for (int i = 0; i < 2; ++i) {
    int g = tid + 256 * i;
    int sl = g & 63, e8 = (g >> 6) * 8;
    uint4 vv = *(const uint4*)(src + sl * 64 + e8);
    const u16* t8 = (const u16*)&vv;
    #pragma unroll
    for (int j = 0; j < 8; ++j) {
      int e = e8 + j;
      t_l[e * 72 + (((sl >> 3) ^ (e & 7)) << 3) + (sl & 7)] = t8[j];
    }
  }
  __syncthreads();
  {
    int e = tid >> 2, c0 = (tid & 3) * 2;
    u16* dst = vt + (((size_t)(b * H_ + h)) * DH_ + e) * S_ + st * 64;
    uint4 x0 = *(const uint4*)(t_l + e * 72 + (((c0    ) ^ (e & 7)) << 3));
    uint4 x1 = *(const uint4*)(t_l + e * 72 + (((c0 + 1) ^ (e & 7)) << 3));
    *(uint4*)(dst + c0 * 8)     = x0;
    *(uint4*)(dst + c0 * 8 + 8) = x1;
  }
}

// ---------------------------------------------------------------------------
// Q/K/V projection: LDS-free GEMM, direct global MFMA fragments.
// A = converted bf16 input (k-contig), B = wt (k-contig). 128x128 block tile,
// 64x64 wave tile, BK=32. Q output pre-scaled by EFACT. grid (32,8,3).
// ---------------------------------------------------------------------------
__global__ __launch_bounds__(256) void proj_kernel(
    const u16* __restrict__ conv, const u16* __restrict__ wt,
    u16* __restrict__ qo, u16* __restrict__ ko, u16* __restrict__ vo)
{
  const int z = blockIdx.z;
  const u16* A    = conv + ((z == 0) ? OFF_QB : (z == 1) ? OFF_KB : OFF_VB);
  const u16* Wz   = wt + (size_t)z * (H_ * DH_ * HID_);
  const u16* bias = conv + OFF_BQ + z * 1024;
  u16*       O    = (z == 0) ? qo : (z == 1) ? ko : vo;
  const float ef  = (z == 0) ? EFACT : 1.0f;
  const int rt = blockIdx.x, ct = blockIdx.y;
  const int tid = threadIdx.x, lane = tid & 63, w = tid >> 6, quad = lane >> 4, l16 = lane & 15;
  const int mq = (w & 1) * 64, nq = (w >> 1) * 64;

  const u16* ap[4];
  const u16* bp[4];
  #pragma unroll
  for (int i = 0; i < 4; ++i) {
    ap[i] = A  + (size_t)(rt * 128 + mq + i * 16 + l16) * HID_ + quad * 8;
    bp[i] = Wz + (size_t)(ct * 128 + nq + i * 16 + l16) * HID_ + quad * 8;
  }

  floatx4 acc[4][4];
  #pragma unroll
  for (int i = 0; i < 4; ++i)
    #pragma unroll
    for (int j = 0; j < 4; ++j) acc[i][j] = (floatx4){0.f,0.f,0.f,0.f};

  for (int kk = 0; kk < 32; ++kk) {
    short8 af[4], bfr[4];
    #pragma unroll
    for (int i = 0; i < 4; ++i) {
      af[i]  = *(const short8*)(ap[i] + kk * 32);
      bfr[i] = *(const short8*)(bp[i] + kk * 32);
    }
    #pragma unroll
    for (int i = 0; i < 4; ++i)
      #pragma unroll
      for (int j = 0; j < 4; ++j)
        acc[i][j] = mfma_bf16(af[i], bfr[j], acc[i][j]);
  }

  #pragma unroll
  for (int j = 0; j < 4; ++j) {
    int col = ct * 128 + nq + j * 16 + l16;
    int hh = col >> 6, e = col & 63;
    float bb = bf2f(bias[col]);
    #pragma unroll
    for (int i = 0; i < 4; ++i) {
      #pragma unroll
      for (int r = 0; r < 4; ++r) {
        int m = rt * 128 + mq + i * 16 + quad * 4 + r;
        int bidx = m >> 10, srow = m & 1023;
        O[(((size_t)(bidx * H_ + hh)) * S_ + srow) * DH_ + e] = f2bf((acc[i][j][r] + bb) * ef);
      }
    }
  }
}

// ---------------------------------------------------------------------------
// Fused attention, barrier-free K-loop: all MFMA fragments loaded directly
// from global (K natural [s][e], V pre-transposed [e][s], Q pre-scaled).
// P round-trips LDS within-wave. Indicator cols: 0=far-lo sum, 1=far-hi sum,
// 2=total softmax denom. One barrier total (epilogue relv^T stage).
// grid (16 qt, 16 h, 4 b), block 256.
// ---------------------------------------------------------------------------
__global__ __launch_bounds__(256) void attn_kernel(
    const u16* __restrict__ Qs, const u16* __restrict__ Ks, const u16* __restrict__ VTs,
    const u16* __restrict__ conv, u16* __restrict__ Ox)
{
  const int qt = blockIdx.x, h = blockIdx.y, b = blockIdx.z;
  const int tid = threadIdx.x;
  const int lane = tid & 63, w = tid >> 6, quad = lane >> 4, l16 = lane & 15;
  const size_t base = ((size_t)(b * H_ + h)) * S_ * DH_;
  const u16* Qb = Qs + base;
  const u16* Kb = Ks + base;
  const u16* Vb = VTs + base;
  const u16* relk = conv + OFF_RELK;
  const u16* relv = conv + OFF_RELV;

  __shared__ __align__(16) u16 p_l[64 * 76];     // 9728 B  (P; epilogue: Bfull)
  __shared__ __align__(16) u16 rvT[64 * 72];     // 9216 B  (epilogue relv^T)
  __shared__ u16 rq_l[64 * 36];                  // 4608 B
  __shared__ float bucket[64 * 34];              // 8704 B

  const int m0 = w * 16;
  short8 qa0 = *(const short8*)(Qb + (size_t)(qt * 64 + m0 + l16) * DH_ + quad * 8);
  short8 qa1 = *(const short8*)(Qb + (size_t)(qt * 64 + m0 + l16) * DH_ + 32 + quad * 8);

  // rq[m][d] = qscaled[m,:] . relk[d,:]  (rows d>=33 discarded; reads stay in-bounds)
  #pragma unroll
  for (int t3 = 0; t3 < 3; ++t3) {
    int d = t3 * 16 + l16;
    short8 kb0 = *(const short8*)(relk + d * 64 + quad * 8);
    short8 kb1 = *(const short8*)(relk + d * 64 + 32 + quad * 8);
    floatx4 c = {0.f,0.f,0.f,0.f};
    c = mfma_bf16(qa0, kb0, c);
    c = mfma_bf16(qa1, kb1, c);
    if (d < NDIST) {
      #pragma unroll
      for (int r = 0; r < 4; ++r) rq_l[(m0 + quad * 4 + r) * 36 + d] = f2bf(c[r]);
    }
  }
  // per-wave zero of own bucket rows (rows m0..m0+15 are flat [m0*34, m0*34+544))
  for (int i = lane; i < 16 * 34; i += 64) bucket[m0 * 34 + i] = 0.f;

  // hoisted far-tile rq values (dist 0 / 32)
  float rqlo[4], rqhi[4];
  #pragma unroll
  for (int r = 0; r < 4; ++r) {
    int m = m0 + quad * 4 + r;
    rqlo[r] = bf2f(rq_l[m * 36 + 0]);
    rqhi[r] = bf2f(rq_l[m * 36 + 32]);
  }

  floatx4 o[4], oi = {0.f,0.f,0.f,0.f};
  #pragma unroll
  for (int t = 0; t < 4; ++t) o[t] = (floatx4){0.f,0.f,0.f,0.f};

  for (int kt = 0; kt < 16; ++kt) {
    const int dkt = kt - qt;
    const bool near = (dkt >= -1) && (dkt <= 1);
    const u16* Kt = Kb + (size_t)kt * 64 * DH_;

    #pragma unroll
    for (int t = 0; t < 4; ++t) {
      int krow = t * 16 + l16;
      short8 kb0 = *(const short8*)(Kt + krow * 64 + quad * 8);
      short8 kb1 = *(const short8*)(Kt + krow * 64 + 32 + quad * 8);
      floatx4 s = {0.f,0.f,0.f,0.f};
      s = mfma_bf16(qa0, kb0, s);
      s = mfma_bf16(qa1, kb1, s);
      int kcol = t * 16 + l16;
      if (!near) {
        const float* rqs = (dkt < 0) ? rqlo : rqhi;
        #pragma unroll
        for (int r = 0; r < 4; ++r) {
          int m = m0 + quad * 4 + r;
          float p = exp2_fast(fminf(s[r] + rqs[r], 30.f));
          p_l[m * 76 + kcol] = f2bf(p);
        }
      } else {
        #pragma unroll
        for (int r = 0; r < 4; ++r) {
          int m = m0 + quad * 4 + r;
          int delta = (kt * 64 + kcol) - (qt * 64 + m);
          int dist = (delta < -16 ? -16 : (delta > 16 ? 16 : delta)) + 16;
          float p = exp2_fast(fminf(s[r] + bf2f(rq_l[m * 36 + dist]), 30.f));
          u16 pu = f2bf(p);
          p_l[m * 76 + kcol] = pu;
          float pv2 = bf2f(pu);
          float vhi = (dist == 32) ? pv2 : 0.f;
          float vlo = (dist == 0) ? pv2 : 0.f;
          #pragma unroll
          for (int off2 = 1; off2 < 16; off2 <<= 1) {
            vhi += __shfl_xor(vhi, off2, 16);
            vlo += __shfl_xor(vlo, off2, 16);
          }
          if (l16 == 0) {
            if (vhi != 0.f) atomicAdd(&bucket[m * 34 + 32], vhi);
            if (vlo != 0.f) atomicAdd(&bucket[m * 34 + 0], vlo);
          }
          if (dist > 0 && dist < 32) atomicAdd(&bucket[m * 34 + dist], pv2);
        }
      }
    }

    // PV + indicator sums (same-wave P round-trip; no barrier)
    short8 pa0 = *(const short8*)(p_l + (m0 + l16) * 76 + quad * 8);
    short8 pa1 = *(const short8*)(p_l + (m0 + l16) * 76 + 32 + quad * 8);
    u16 iv = 0;
    if (l16 == 2) iv = 0x3F80;
    else if (l16 == 0 && dkt <= -2) iv = 0x3F80;
    else if (l16 == 1 && dkt >= 2) iv = 0x3F80;
    short8 ib;
    #pragma unroll
    for (int j = 0; j < 8; ++j) ib[j] = (short)iv;
    oi = mfma_bf16(pa0, ib, oi);
    oi = mfma_bf16(pa1, ib, oi);
    #pragma unroll
    for (int t = 0; t < 4; ++t) {
      int e = t * 16 + l16;
      short8 vb0 = *(const short8*)(Vb + (size_t)e * S_ + kt * 64 + quad * 8);
      short8 vb1 = *(const short8*)(Vb + (size_t)e * S_ + kt * 64 + 32 + quad * 8);
      o[t] = mfma_bf16(pa0, vb0, o[t]);
      o[t] = mfma_bf16(pa1, vb1, o[t]);
    }
  }

  // fold far sums into own bucket rows (cols 0 / 32); own-wave only, no barrier
  if (l16 == 0) {
    #pragma unroll
    for (int r = 0; r < 4; ++r) bucket[(m0 + quad * 4 + r) * 34 + 0] += oi[r];
  } else if (l16 == 1) {
    #pragma unroll
    for (int r = 0; r < 4; ++r) bucket[(m0 + quad * 4 + r) * 34 + 32] += oi[r];
  }
  // softmax denominators from indicator col 2 (lane quad*16+2 holds them)
  float rl[4];
  #pragma unroll
  for (int r = 0; r < 4; ++r) {
    float lv = __shfl(oi[r], (lane & 48) + 2, 64);
    rl[r] = 1.f / lv;
  }

  // cooperative relv^T stage (zero-filled cols d>=33), per-wave Bfull into p_l
  for (int i = tid; i < 4096; i += 256) {
    int d = i >> 6, e = i & 63;
    rvT[e * 72 + d] = (d < NDIST) ? relv[d * 64 + e] : (u16)0;
  }
  #pragma unroll
  for (int it = 0; it < 16; ++it) {
    int m = m0 + it;
    p_l[m * 76 + lane] = (lane < NDIST) ? f2bf(bucket[m * 34 + lane]) : (u16)0;
  }
  __syncthreads();

  // o += Bfull @ relv
  short8 ba0 = *(const short8*)(p_l + (m0 + l16) * 76 + quad * 8);
  short8 ba1 = *(const short8*)(p_l + (m0 + l16) * 76 + 32 + quad * 8);
  #pragma unroll
  for (int t = 0; t < 4; ++t) {
    short8 rb0 = *(const short8*)(rvT + (t * 16 + l16) * 72 + quad * 8);
    short8 rb1 = *(const short8*)(rvT + (t * 16 + l16) * 72 + 32 + quad * 8);
    o[t] = mfma_bf16(ba0, rb0, o[t]);
    o[t] = mfma_bf16(ba1, rb1, o[t]);
  }

  #pragma unroll
  for (int t = 0; t < 4; ++t) {
    int e = t * 16 + l16;
    #pragma unroll
    for (int r = 0; r < 4; ++r) {
      int srow = qt * 64 + m0 + quad * 4 + r;
      Ox[((size_t)(b * S_ + srow)) * HID_ + h * 64 + e] = f2bf(o[t][r] * rl[r]);
    }
  }
}

// ---------------------------------------------------------------------------
// fc: LDS-free GEMM, out = X @ fcW^T + b. Dual-dtype output. grid (32,8).
// ---------------------------------------------------------------------------
__global__ __launch_bounds__(256) void fc_kernel(
    const u16* __restrict__ X, const u16* __restrict__ conv,
    const int* __restrict__ flag, void* __restrict__ outv)
{
  const u16* Wf  = conv + OFF_FCW;
  const u16* bfc = conv + OFF_FCB;
  const int rt = blockIdx.x, ct = blockIdx.y;
  const int tid = threadIdx.x, lane = tid & 63, w = tid >> 6, quad = lane >> 4, l16 = lane & 15;
  const int isf = *flag;
  const int mq = (w & 1) * 64, nq = (w >> 1) * 64;

  const u16* ap[4];
  const u16* bp[4];
  #pragma unroll
  for (int i = 0; i < 4; ++i) {
    ap[i] = X  + (size_t)(rt * 128 + mq + i * 16 + l16) * HID_ + quad * 8;
    bp[i] = Wf + (size_t)(ct * 128 + nq + i * 16 + l16) * HID_ + quad * 8;
  }

  floatx4 acc[4][4];
  #pragma unroll
  for (int i = 0; i < 4; ++i)
    #pragma unroll
    for (int j = 0; j < 4; ++j) acc[i][j] = (floatx4){0.f,0.f,0.f,0.f};

  for (int kk = 0; kk < 32; ++kk) {
    short8 af[4], bfr[4];
    #pragma unroll
    for (int i = 0; i < 4; ++i) {
      af[i]  = *(const short8*)(ap[i] + kk * 32);
      bfr[i] = *(const short8*)(bp[i] + kk * 32);
    }
    #pragma unroll
    for (int i = 0; i < 4; ++i)
      #pragma unroll
      for (int j = 0; j < 4; ++j)
        acc[i][j] = mfma_bf16(af[i], bfr[j], acc[i][j]);
  }

  #pragma unroll
  for (int j = 0; j < 4; ++j) {
    int col = ct * 128 + nq + j * 16 + l16;
    float bb = bf2f(bfc[col]);
    #pragma unroll
    for (int i = 0; i < 4; ++i) {
      #pragma unroll
      for (int r = 0; r < 4; ++r) {
        int m = rt * 128 + mq + i * 16 + quad * 4 + r;
        float val = acc[i][j][r] + bb;
        size_t idx = (size_t)m * HID_ + col;
        if (isf) ((float*)outv)[idx] = val;
        else     ((u16*)outv)[idx]   = f2bf(val);
      }
    }
  }
}

extern "C" void kernel_launch(void* const* d_in, const int* in_sizes, int n_in,
                              void* d_out, int out_size, void* d_ws, size_t ws_size,
                              hipStream_t stream) {
  int* flag = (int*)d_ws;
  u16* conv = (u16*)((char*)d_ws + 16);
  u16* wt   = conv + CONV_TOT;                 // 3,145,728 elems
  u16* qw   = wt + 3145728;                    // [B,H,S,DH] scaled Q
  u16* kw   = qw + 4194304;
  u16* vw   = kw + 4194304;                    // V natural (dead after vtrans)
  u16* vt   = conv + OFF_QB;                   // V^T [B,H,DH,S] — reuses QB (dead after proj)
  u16* xw   = vw;                              // attn out — reuses vw (dead after attn... vtrans)

  detect_kernel<<<1, 256, 0, stream>>>((const u16*)d_in[0], flag);

  SrcPtrs sp;
  sp.p[0] = d_in[0];  sp.p[1] = d_in[1];  sp.p[2] = d_in[2];
  sp.p[3] = d_in[4];  sp.p[4] = d_in[6];  sp.p[5] = d_in[8];
  sp.p[6] = d_in[9];  sp.p[7] = d_in[10]; sp.p[8] = d_in[11]; sp.p[9] = d_in[12];
  convert_kernel<<<13322, 256, 0, stream>>>(sp, flag, conv);

  wtrans_kernel<<<dim3(16, 16, 3), 256, 0, stream>>>(d_in[3], d_in[5], d_in[7], flag, wt);
  proj_kernel<<<dim3(32, 8, 3), 256, 0, stream>>>(conv, wt, qw, kw, vw);
  vtrans_kernel<<<dim3(16, 16, 4), 256, 0, stream>>>(vw, vt);
  attn_kernel<<<dim3(16, 16, 4), 256, 0, stream>>>(qw, kw, vt, conv, xw);
  fc_kernel<<<dim3(32, 8), 256, 0, stream>>>(xw, conv, flag, d_out);
}

// Round 8
// 369.513 us; speedup vs baseline: 1.1176x; 1.1176x over previous
//
#include <hip/hip_runtime.h>
#include <stdint.h>

#define B_ 4
#define S_ 1024
#define HID_ 1024
#define H_ 16
#define DH_ 64
#define NDIST 33
// SCALE * log2(e) folded into Q at proj epilogue; softmax = exp2(s + rq)
#define EFACT 0.18033688f

typedef unsigned short u16;
typedef __attribute__((ext_vector_type(8))) short short8;
typedef __attribute__((ext_vector_type(4))) float floatx4;

static __device__ __forceinline__ float bf2f(u16 u) {
  union { unsigned int i; float f; } v; v.i = ((unsigned int)u) << 16; return v.f;
}
static __device__ __forceinline__ u16 f2bf(float x) {
  union { float f; unsigned int i; } v; v.f = x;
  return (u16)((v.i + 0x7FFFu + ((v.i >> 16) & 1u)) >> 16);
}
static __device__ __forceinline__ floatx4 mfma_bf16(short8 a, short8 b, floatx4 c) {
  return __builtin_amdgcn_mfma_f32_16x16x32_bf16(a, b, c, 0, 0, 0);
}
static __device__ __forceinline__ float exp2_fast(float x) {
#if __has_builtin(__builtin_amdgcn_exp2f)
  return __builtin_amdgcn_exp2f(x);
#else
  return __expf(x * 0.6931471805599453f);
#endif
}

// conv region element offsets (u16 units)
#define OFF_QB   0
#define OFF_KB   4194304
#define OFF_VB   8388608
#define OFF_BQ   12582912
#define OFF_BK   12583936
#define OFF_BV   12584960
#define OFF_RELK 12585984
#define OFF_RELV 12588096
#define OFF_FCW  12590208
#define OFF_FCB  13638784
#define CONV_TOT 13639808

struct SrcPtrs { const void* p[10]; };

// ---------------------------------------------------------------------------
// Dtype detector: fp32 read as u16 pairs -> even halves huge as bf16.
// ---------------------------------------------------------------------------
__global__ __launch_bounds__(256) void detect_kernel(const u16* __restrict__ q,
                                                     int* __restrict__ flag) {
  __shared__ float red[256];
  float m = 0.f;
  for (int i = threadIdx.x; i < 8192; i += 256) {
    float v = fabsf(bf2f(q[2 * i]));
    m = fmaxf(m, (v < 1e30f) ? v : 1e20f);
  }
  red[threadIdx.x] = m;
  __syncthreads();
  for (int s = 128; s > 0; s >>= 1) {
    if (threadIdx.x < (unsigned)s) red[threadIdx.x] = fmaxf(red[threadIdx.x], red[threadIdx.x + s]);
    __syncthreads();
  }
  if (threadIdx.x == 0) *flag = (red[0] > 1e4f) ? 1 : 0;
}

// ---------------------------------------------------------------------------
// Convert q/k/v inputs + biases / rel tables / fcW to bf16 (copy if bf16).
// ---------------------------------------------------------------------------
__global__ __launch_bounds__(256) void convert_kernel(SrcPtrs srcs,
                                                      const int* __restrict__ flag,
                                                      u16* __restrict__ dst) {
  constexpr int segsz[10] = {4194304,4194304,4194304,1024,1024,1024,2112,2112,1048576,1024};
  constexpr int cumE[10]  = {OFF_QB,OFF_KB,OFF_VB,OFF_BQ,OFF_BK,OFF_BV,OFF_RELK,OFF_RELV,OFF_FCW,OFF_FCB};
  constexpr int cumB[10]  = {0,4096,8192,12288,12289,12290,12291,12294,12297,13321};
  const int bid = blockIdx.x;
  int t = 0;
  #pragma unroll
  for (int i = 1; i < 10; ++i) if (bid >= cumB[i]) t = i;
  const int chunk = (bid - cumB[t]) * 1024 + threadIdx.x * 4;
  if (chunk >= segsz[t]) return;
  __align__(8) u16 o[4];
  if (*flag) {
    const float* s = (const float*)srcs.p[t];
    float4 v = *(const float4*)(s + chunk);
    o[0] = f2bf(v.x); o[1] = f2bf(v.y); o[2] = f2bf(v.z); o[3] = f2bf(v.w);
  } else {
    const u16* s = (const u16*)srcs.p[t];
    *(uint2*)o = *(const uint2*)(s + chunk);
  }
  *(uint2*)(dst + cumE[t] + chunk) = *(const uint2*)o;
}

// ---------------------------------------------------------------------------
// W transpose: raw W [h][d][e] (fp32 or bf16) -> wt[z][h*64+e][d] bf16.
// ---------------------------------------------------------------------------
__global__ __launch_bounds__(256) void wtrans_kernel(
    const void* __restrict__ Wq, const void* __restrict__ Wk, const void* __restrict__ Wv,
    const int* __restrict__ flag, u16* __restrict__ wt)
{
  const int dt = blockIdx.x, h = blockIdx.y, z = blockIdx.z;
  const void* W = (z == 0) ? Wq : (z == 1) ? Wk : Wv;
  const int tid = threadIdx.x;
  const int isf = *flag;
  __shared__ __align__(16) u16 t_l[64 * 72];

  #pragma unroll
  for (int i = 0; i < 2; ++i) {
    int g = tid + 256 * i;
    int d = g & 63, e8 = (g >> 6) * 8;
    size_t off = ((size_t)h * HID_ + dt * 64 + d) * DH_ + e8;
    __align__(16) u16 tmp[8];
    if (isf) {
      const float* Wf = (const float*)W + off;
      float4 v0 = *(const float4*)Wf;
      float4 v1 = *(const float4*)(Wf + 4);
      tmp[0]=f2bf(v0.x); tmp[1]=f2bf(v0.y); tmp[2]=f2bf(v0.z); tmp[3]=f2bf(v0.w);
      tmp[4]=f2bf(v1.x); tmp[5]=f2bf(v1.y); tmp[6]=f2bf(v1.z); tmp[7]=f2bf(v1.w);
    } else {
      *(uint4*)tmp = *(const uint4*)((const u16*)W + off);
    }
    #pragma unroll
    for (int j = 0; j < 8; ++j) {
      int e = e8 + j;
      t_l[e * 72 + (((d >> 3) ^ (e & 7)) << 3) + (d & 7)] = tmp[j];
    }
  }
  __syncthreads();
  {
    int e = tid >> 2, c0 = (tid & 3) * 2;
    u16* dst = wt + ((size_t)(z * H_ + h) * DH_ + e) * HID_ + dt * 64;
    uint4 x0 = *(const uint4*)(t_l + e * 72 + (((c0    ) ^ (e & 7)) << 3));
    uint4 x1 = *(const uint4*)(t_l + e * 72 + (((c0 + 1) ^ (e & 7)) << 3));
    *(uint4*)(dst + c0 * 8)     = x0;
    *(uint4*)(dst + c0 * 8 + 8) = x1;
  }
}

// ---------------------------------------------------------------------------
// Q/K/V projection GEMM (R3-verified staged structure): 128x128 tile, BK=32,
// VGPR-round-trip uint4 staging. A = converted bf16. z=0 output pre-scaled by
// EFACT. Natural [b][h][s][dh] store. grid (32, 8, 3), block 256.
// ---------------------------------------------------------------------------
__global__ __launch_bounds__(256) void proj_kernel(
    const u16* __restrict__ conv, const u16* __restrict__ wt,
    u16* __restrict__ qo, u16* __restrict__ ko, u16* __restrict__ vo)
{
  const int z = blockIdx.z;
  const u16* A    = conv + ((z == 0) ? OFF_QB : (z == 1) ? OFF_KB : OFF_VB);
  const u16* Wz   = wt + (size_t)z * (H_ * DH_ * HID_);
  const u16* bias = conv + OFF_BQ + z * 1024;
  u16*       O    = (z == 0) ? qo : (z == 1) ? ko : vo;
  const float ef  = (z == 0) ? EFACT : 1.0f;
  const int rt = blockIdx.x, ct = blockIdx.y;
  const int tid = threadIdx.x, lane = tid & 63, w = tid >> 6, quad = lane >> 4, l16 = lane & 15;
  const int mq = (w & 1) * 64, nq = (w >> 1) * 64;

  __shared__ __align__(16) u16 a_l[128 * 32];
  __shared__ __align__(16) u16 b_l[128 * 32];

  floatx4 acc[4][4];
  #pragma unroll
  for (int i = 0; i < 4; ++i)
    #pragma unroll
    for (int j = 0; j < 4; ++j) acc[i][j] = (floatx4){0.f,0.f,0.f,0.f};

  for (int kk = 0; kk < 32; ++kk) {
    __syncthreads();
    #pragma unroll
    for (int i = 0; i < 2; ++i) {
      int idx = tid + 256 * i;
      int row = idx >> 2, c8 = (idx & 3) * 8;
      *(uint4*)(a_l + row * 32 + c8) =
          *(const uint4*)(A + (size_t)(rt * 128 + row) * HID_ + kk * 32 + c8);
      *(uint4*)(b_l + row * 32 + c8) =
          *(const uint4*)(Wz + (size_t)(ct * 128 + row) * HID_ + kk * 32 + c8);
    }
    __syncthreads();
    short8 af[4], bfr[4];
    #pragma unroll
    for (int i = 0; i < 4; ++i) {
      af[i]  = *(const short8*)(a_l + (mq + i * 16 + l16) * 32 + quad * 8);
      bfr[i] = *(const short8*)(b_l + (nq + i * 16 + l16) * 32 + quad * 8);
    }
    #pragma unroll
    for (int i = 0; i < 4; ++i)
      #pragma unroll
      for (int j = 0; j < 4; ++j)
        acc[i][j] = mfma_bf16(af[i], bfr[j], acc[i][j]);
  }

  #pragma unroll
  for (int j = 0; j < 4; ++j) {
    int col = ct * 128 + nq + j * 16 + l16;
    int hh = col >> 6, e = col & 63;
    float bb = bf2f(bias[col]);
    #pragma unroll
    for (int i = 0; i < 4; ++i) {
      #pragma unroll
      for (int r = 0; r < 4; ++r) {
        int m = rt * 128 + mq + i * 16 + quad * 4 + r;
        int bidx = m >> 10, srow = m & 1023;
        O[(((size_t)(bidx * H_ + hh)) * S_ + srow) * DH_ + e] = f2bf((acc[i][j][r] + bb) * ef);
      }
    }
  }
}

// ---------------------------------------------------------------------------
// V transpose (verified): vw [b][h][s][e] -> vt [b][h][e][s].
// grid (16 s-tiles, 16 h, 4 b), block 256.
// ---------------------------------------------------------------------------
__global__ __launch_bounds__(256) void vtrans_kernel(
    const u16* __restrict__ vw, u16* __restrict__ vt)
{
  const int st = blockIdx.x, h = blockIdx.y, b = blockIdx.z;
  const int tid = threadIdx.x;
  const u16* src = vw + (((size_t)(b * H_ + h)) * S_ + st * 64) * DH_;
  __shared__ __align__(16) u16 t_l[64 * 72];

  #pragma unroll
  for (int i = 0; i < 2; ++i) {
    int g = tid + 256 * i;
    int sl = g & 63, e8 = (g >> 6) * 8;
    uint4 vv = *(const uint4*)(src + sl * 64 + e8);
    const u16* t8 = (const u16*)&vv;
    #pragma unroll
    for (int j = 0; j < 8; ++j) {
      int e = e8 + j;
      t_l[e * 72 + (((sl >> 3) ^ (e & 7)) << 3) + (sl & 7)] = t8[j];
    }
  }
  __syncthreads();
  {
    int e = tid >> 2, c0 = (tid & 3) * 2;
    u16* dst = vt + (((size_t)(b * H_ + h)) * DH_ + e) * S_ + st * 64;
    uint4 x0 = *(const uint4*)(t_l + e * 72 + (((c0    ) ^ (e & 7)) << 3));
    uint4 x1 = *(const uint4*)(t_l + e * 72 + (((c0 + 1) ^ (e & 7)) << 3));
    *(uint4*)(dst + c0 * 8)     = x0;
    *(uint4*)(dst + c0 * 8 + 8) = x1;
  }
}

// ---------------------------------------------------------------------------
// Fused attention — ROUND-4-PASSED v3, restored VERBATIM. Barrier-free K-loop,
// direct global MFMA fragments (K natural [s][e], V^T [e][s], Q pre-scaled).
// Interior rel-v buckets via LDS float atomics; near-tile edges via width-16
// shfl + atomicAdd; far tiles via indicator cols (0=far-lo, 1=far-hi,
// 2=softmax denom). One __syncthreads total. grid (16 qt, 16 h, 4 b).
// ---------------------------------------------------------------------------
__global__ __launch_bounds__(256) void attn_kernel(
    const u16* __restrict__ Qs, const u16* __restrict__ Ks, const u16* __restrict__ VTs,
    const u16* __restrict__ conv, u16* __restrict__ Ox)
{
  const int qt = blockIdx.x, h = blockIdx.y, b = blockIdx.z;
  const int tid = threadIdx.x;
  const int lane = tid & 63, w = tid >> 6, quad = lane >> 4, l16 = lane & 15;
  const size_t base = ((size_t)(b * H_ + h)) * S_ * DH_;
  const u16* Qb = Qs + base;
  const u16* Kb = Ks + base;
  const u16* Vb = VTs + base;
  const u16* relk = conv + OFF_RELK;
  const u16* relv = conv + OFF_RELV;

  __shared__ __align__(16) u16 p_l[64 * 76];     // P; epilogue: Bfull
  __shared__ __align__(16) u16 rvT[64 * 72];     // epilogue relv^T
  __shared__ u16 rq_l[64 * 36];                  // rq[m][d] bf16
  __shared__ float bucket[64 * 34];              // rel-v distance buckets

  const int m0 = w * 16;
  short8 qa0 = *(const short8*)(Qb + (size_t)(qt * 64 + m0 + l16) * DH_ + quad * 8);
  short8 qa1 = *(const short8*)(Qb + (size_t)(qt * 64 + m0 + l16) * DH_ + 32 + quad * 8);

  // rq[m][d] = qscaled[m,:] . relk[d,:]  (d>=33 rows read junk, discarded)
  #pragma unroll
  for (int t3 = 0; t3 < 3; ++t3) {
    int d = t3 * 16 + l16;
    short8 kb0 = *(const short8*)(relk + d * 64 + quad * 8);
    short8 kb1 = *(const short8*)(relk + d * 64 + 32 + quad * 8);
    floatx4 c = {0.f,0.f,0.f,0.f};
    c = mfma_bf16(qa0, kb0, c);
    c = mfma_bf16(qa1, kb1, c);
    if (d < NDIST) {
      #pragma unroll
      for (int r = 0; r < 4; ++r) rq_l[(m0 + quad * 4 + r) * 36 + d] = f2bf(c[r]);
    }
  }
  // per-wave zero of own bucket rows
  for (int i = lane; i < 16 * 34; i += 64) bucket[m0 * 34 + i] = 0.f;

  float rqlo[4], rqhi[4];
  #pragma unroll
  for (int r = 0; r < 4; ++r) {
    int m = m0 + quad * 4 + r;
    rqlo[r] = bf2f(rq_l[m * 36 + 0]);
    rqhi[r] = bf2f(rq_l[m * 36 + 32]);
  }

  floatx4 o[4], oi = {0.f,0.f,0.f,0.f};
  #pragma unroll
  for (int t = 0; t < 4; ++t) o[t] = (floatx4){0.f,0.f,0.f,0.f};

  for (int kt = 0; kt < 16; ++kt) {
    const int dkt = kt - qt;
    const bool near = (dkt >= -1) && (dkt <= 1);
    const u16* Kt = Kb + (size_t)kt * 64 * DH_;

    #pragma unroll
    for (int t = 0; t < 4; ++t) {
      int krow = t * 16 + l16;
      short8 kb0 = *(const short8*)(Kt + krow * 64 + quad * 8);
      short8 kb1 = *(const short8*)(Kt + krow * 64 + 32 + quad * 8);
      floatx4 s = {0.f,0.f,0.f,0.f};
      s = mfma_bf16(qa0, kb0, s);
      s = mfma_bf16(qa1, kb1, s);
      int kcol = t * 16 + l16;
      if (!near) {
        const float* rqs = (dkt < 0) ? rqlo : rqhi;
        #pragma unroll
        for (int r = 0; r < 4; ++r) {
          int m = m0 + quad * 4 + r;
          float p = exp2_fast(fminf(s[r] + rqs[r], 30.f));
          p_l[m * 76 + kcol] = f2bf(p);
        }
      } else {
        #pragma unroll
        for (int r = 0; r < 4; ++r) {
          int m = m0 + quad * 4 + r;
          int delta = (kt * 64 + kcol) - (qt * 64 + m);
          int dist = (delta < -16 ? -16 : (delta > 16 ? 16 : delta)) + 16;
          float p = exp2_fast(fminf(s[r] + bf2f(rq_l[m * 36 + dist]), 30.f));
          u16 pu = f2bf(p);
          p_l[m * 76 + kcol] = pu;
          float pv2 = bf2f(pu);
          float vhi = (dist == 32) ? pv2 : 0.f;
          float vlo = (dist == 0) ? pv2 : 0.f;
          #pragma unroll
          for (int off2 = 1; off2 < 16; off2 <<= 1) {
            vhi += __shfl_xor(vhi, off2, 16);
            vlo += __shfl_xor(vlo, off2, 16);
          }
          if (l16 == 0) {
            if (vhi != 0.f) atomicAdd(&bucket[m * 34 + 32], vhi);
            if (vlo != 0.f) atomicAdd(&bucket[m * 34 + 0], vlo);
          }
          if (dist > 0 && dist < 32) atomicAdd(&bucket[m * 34 + dist], pv2);
        }
      }
    }

    // same-wave P round-trip (no barrier)
    short8 pa0 = *(const short8*)(p_l + (m0 + l16) * 76 + quad * 8);
    short8 pa1 = *(const short8*)(p_l + (m0 + l16) * 76 + 32 + quad * 8);
    u16 iv = 0;
    if (l16 == 2) iv = 0x3F80;
    else if (l16 == 0 && dkt <= -2) iv = 0x3F80;
    else if (l16 == 1 && dkt >= 2) iv = 0x3F80;
    short8 ib;
    #pragma unroll
    for (int j = 0; j < 8; ++j) ib[j] = (short)iv;
    oi = mfma_bf16(pa0, ib, oi);
    oi = mfma_bf16(pa1, ib, oi);
    #pragma unroll
    for (int t = 0; t < 4; ++t) {
      int e = t * 16 + l16;
      short8 vb0 = *(const short8*)(Vb + (size_t)e * S_ + kt * 64 + quad * 8);
      short8 vb1 = *(const short8*)(Vb + (size_t)e * S_ + kt * 64 + 32 + quad * 8);
      o[t] = mfma_bf16(pa0, vb0, o[t]);
      o[t] = mfma_bf16(pa1, vb1, o[t]);
    }
  }

  // fold far sums into own bucket rows (cols 0 / 32); own-wave only, no barrier
  if (l16 == 0) {
    #pragma unroll
    for (int r = 0; r < 4; ++r) bucket[(m0 + quad * 4 + r) * 34 + 0] += oi[r];
  } else if (l16 == 1) {
    #pragma unroll
    for (int r = 0; r < 4; ++r) bucket[(m0 + quad * 4 + r) * 34 + 32] += oi[r];
  }
  // softmax denominators from indicator col 2
  float rl[4];
  #pragma unroll
  for (int r = 0; r < 4; ++r) rl[r] = 1.f / __shfl(oi[r], (lane & 48) + 2, 64);

  // cooperative relv^T stage + per-wave Bfull into p_l -> the single barrier
  for (int i = tid; i < 4096; i += 256) {
    int d = i >> 6, e = i & 63;
    rvT[e * 72 + d] = (d < NDIST) ? relv[d * 64 + e] : (u16)0;
  }
  #pragma unroll
  for (int it = 0; it < 16; ++it) {
    int m = m0 + it;
    p_l[m * 76 + lane] = (lane < NDIST) ? f2bf(bucket[m * 34 + lane]) : (u16)0;
  }
  __syncthreads();

  // o += Bfull @ relv
  short8 ba0 = *(const short8*)(p_l + (m0 + l16) * 76 + quad * 8);
  short8 ba1 = *(const short8*)(p_l + (m0 + l16) * 76 + 32 + quad * 8);
  #pragma unroll
  for (int t = 0; t < 4; ++t) {
    short8 rb0 = *(const short8*)(rvT + (t * 16 + l16) * 72 + quad * 8);
    short8 rb1 = *(const short8*)(rvT + (t * 16 + l16) * 72 + 32 + quad * 8);
    o[t] = mfma_bf16(ba0, rb0, o[t]);
    o[t] = mfma_bf16(ba1, rb1, o[t]);
  }

  #pragma unroll
  for (int t = 0; t < 4; ++t) {
    int e = t * 16 + l16;
    #pragma unroll
    for (int r = 0; r < 4; ++r) {
      int srow = qt * 64 + m0 + quad * 4 + r;
      Ox[((size_t)(b * S_ + srow)) * HID_ + h * 64 + e] = f2bf(o[t][r] * rl[r]);
    }
  }
}

// ---------------------------------------------------------------------------
// fc (R3-verified staged structure): out = X @ fcW^T + b. 128x128 tile, BK=32.
// Dual-dtype output. grid (32, 8), block 256.
// ---------------------------------------------------------------------------
__global__ __launch_bounds__(256) void fc_kernel(
    const u16* __restrict__ X, const u16* __restrict__ conv,
    const int* __restrict__ flag, void* __restrict__ outv)
{
  const u16* Wf  = conv + OFF_FCW;
  const u16* bfc = conv + OFF_FCB;
  const int rt = blockIdx.x, ct = blockIdx.y;
  const int tid = threadIdx.x, lane = tid & 63, w = tid >> 6, quad = lane >> 4, l16 = lane & 15;
  const int isf = *flag;
  const int mq = (w & 1) * 64, nq = (w >> 1) * 64;

  __shared__ __align__(16) u16 a_l[128 * 32];
  __shared__ __align__(16) u16 b_l[128 * 32];

  floatx4 acc[4][4];
  #pragma unroll
  for (int i = 0; i < 4; ++i)
    #pragma unroll
    for (int j = 0; j < 4; ++j) acc[i][j] = (floatx4){0.f,0.f,0.f,0.f};

  for (int kk = 0; kk < 32; ++kk) {
    __syncthreads();
    #pragma unroll
    for (int i = 0; i < 2; ++i) {
      int idx = tid + 256 * i;
      int row = idx >> 2, c8 = (idx & 3) * 8;
      *(uint4*)(a_l + row * 32 + c8) =
          *(const uint4*)(X + (size_t)(rt * 128 + row) * HID_ + kk * 32 + c8);
      *(uint4*)(b_l + row * 32 + c8) =
          *(const uint4*)(Wf + (size_t)(ct * 128 + row) * HID_ + kk * 32 + c8);
    }
    __syncthreads();
    short8 af[4], bfr[4];
    #pragma unroll
    for (int i = 0; i < 4; ++i) {
      af[i]  = *(const short8*)(a_l + (mq + i * 16 + l16) * 32 + quad * 8);
      bfr[i] = *(const short8*)(b_l + (nq + i * 16 + l16) * 32 + quad * 8);
    }
    #pragma unroll
    for (int i = 0; i < 4; ++i)
      #pragma unroll
      for (int j = 0; j < 4; ++j)
        acc[i][j] = mfma_bf16(af[i], bfr[j], acc[i][j]);
  }

  #pragma unroll
  for (int j = 0; j < 4; ++j) {
    int col = ct * 128 + nq + j * 16 + l16;
    float bb = bf2f(bfc[col]);
    #pragma unroll
    for (int i = 0; i < 4; ++i) {
      #pragma unroll
      for (int r = 0; r < 4; ++r) {
        int m = rt * 128 + mq + i * 16 + quad * 4 + r;
        float val = acc[i][j][r] + bb;
        size_t idx = (size_t)m * HID_ + col;
        if (isf) ((float*)outv)[idx] = val;
        else     ((u16*)outv)[idx]   = f2bf(val);
      }
    }
  }
}

extern "C" void kernel_launch(void* const* d_in, const int* in_sizes, int n_in,
                              void* d_out, int out_size, void* d_ws, size_t ws_size,
                              hipStream_t stream) {
  int* flag = (int*)d_ws;
  u16* conv = (u16*)((char*)d_ws + 16);
  u16* wt   = conv + CONV_TOT;                 // 3,145,728 elems
  u16* qw   = wt + 3145728;                    // scaled Q [B,H,S,DH]
  u16* kw   = qw + 4194304;                    // K [B,H,S,DH]
  u16* vw   = kw + 4194304;                    // V natural (dead after vtrans)
  u16* vt   = conv + OFF_QB;                   // V^T [B,H,DH,S] — reuses QB (dead after proj)
  u16* xw   = vw;                              // attn out — reuses vw (dead after vtrans)

  detect_kernel<<<1, 256, 0, stream>>>((const u16*)d_in[0], flag);

  SrcPtrs sp;
  sp.p[0] = d_in[0];  sp.p[1] = d_in[1];  sp.p[2] = d_in[2];
  sp.p[3] = d_in[4];  sp.p[4] = d_in[6];  sp.p[5] = d_in[8];
  sp.p[6] = d_in[9];  sp.p[7] = d_in[10]; sp.p[8] = d_in[11]; sp.p[9] = d_in[12];
  convert_kernel<<<13322, 256, 0, stream>>>(sp, flag, conv);

  wtrans_kernel<<<dim3(16, 16, 3), 256, 0, stream>>>(d_in[3], d_in[5], d_in[7], flag, wt);
  proj_kernel<<<dim3(32, 8, 3), 256, 0, stream>>>(conv, wt, qw, kw, vw);
  vtrans_kernel<<<dim3(16, 16, 4), 256, 0, stream>>>(vw, vt);
  attn_kernel<<<dim3(16, 16, 4), 256, 0, stream>>>(qw, kw, vt, conv, xw);
  fc_kernel<<<dim3(32, 8), 256, 0, stream>>>(xw, conv, flag, d_out);
}